// Round 14
// baseline (144.990 us; speedup 1.0000x reference)
//
#include <hip/hip_runtime.h>

#define BATCH 16
#define NNODES 50000
#define NEDGES 1600000
#define BN (BATCH * NNODES)
#define CLAMP_LO -10.0f
#define CLAMP_HI 10.0f
#define EPS_V 1e-6f

// ---- geometry ----
#define NBINS 782               // bins of 64 nodes; 782*64 = 50048 >= 50000
#define BSZ 64                  // nodes per bin
#define CAPE 2560               // LDS edge cap per bin: Poisson(2046) + 11.4 sd
#define K1B 250                 // kernel-1 blocks (slices)
#define EPS 6400                // edges per slice; 250*6400 = 1.6M exact
#define E4PS 1600               // int4s per slice
#define NPT 200                 // nodes transposed per k1 block; 250*200 = 50000
#define HROW 784                // hist row stride (783 starts, padded)

// ---- kernel 1: transpose + slice-local bin sort (deterministic, no global atomics) ----
__global__ __launch_bounds__(256) void slice_sort(
    const float* __restrict__ o_pre, const float* __restrict__ E,
    const int* __restrict__ src, const int* __restrict__ dst,
    const float* __restrict__ w,
    float* __restrict__ o_t, float* __restrict__ E_t,
    int* __restrict__ hist,        // [K1B][HROW] local bin starts (start[782]=6400)
    uint2* __restrict__ binned) {  // [K1B][EPS] slice-local, bin-sorted
    __shared__ int lh[NBINS];      // counts
    __shared__ int cur[NBINS];     // scatter cursors (slice-local)
    __shared__ int sm[256];
    const int tid = threadIdx.x, bid = blockIdx.x;

    for (int i = tid; i < NBINS; i += 256) lh[i] = 0;

    // transpose nodes [bid*200, bid*200+200)
    if (tid < NPT) {
        int t = bid * NPT + tid;
        float v[BATCH], u[BATCH];
#pragma unroll
        for (int b = 0; b < BATCH; ++b) {
            v[b] = o_pre[b * NNODES + t];   // coalesced across t
            u[b] = E[b * NNODES + t];
        }
        float4* op = (float4*)(o_t + (size_t)t * BATCH);
        float4* ep = (float4*)(E_t + (size_t)t * BATCH);
#pragma unroll
        for (int k = 0; k < 4; ++k) {
            op[k] = make_float4(v[4 * k], v[4 * k + 1], v[4 * k + 2], v[4 * k + 3]);
            ep[k] = make_float4(u[4 * k], u[4 * k + 1], u[4 * k + 2], u[4 * k + 3]);
        }
    }
    __syncthreads();  // lh zeroed

    // pass A: histogram this slice (int4 loads)
    const int4* dst4 = (const int4*)dst;
    const int i40 = bid * E4PS;
#pragma unroll
    for (int j = 0; j < 7; ++j) {
        int idx = j * 256 + tid;
        if (idx < E4PS) {
            int4 d4 = dst4[i40 + idx];
            atomicAdd(&lh[d4.x >> 6], 1);
            atomicAdd(&lh[d4.y >> 6], 1);
            atomicAdd(&lh[d4.z >> 6], 1);
            atomicAdd(&lh[d4.w >> 6], 1);
        }
    }
    __syncthreads();

    // block-scan 782 counts -> exclusive starts; thread t owns bins 4t..4t+3
    {
        int base = tid * 4;
        int v[4], psum = 0;
#pragma unroll
        for (int j = 0; j < 4; ++j) {
            int idx = base + j;
            v[j] = (idx < NBINS) ? lh[idx] : 0;
            psum += v[j];
        }
        sm[tid] = psum;
        __syncthreads();
        for (int off = 1; off < 256; off <<= 1) {
            int a = (tid >= off) ? sm[tid - off] : 0;
            __syncthreads();
            sm[tid] += a;
            __syncthreads();
        }
        int run = (tid > 0) ? sm[tid - 1] : 0;
#pragma unroll
        for (int j = 0; j < 4; ++j) {
            int idx = base + j;
            if (idx < NBINS + 1) {           // write starts 0..782 (782 = total)
                hist[(size_t)bid * HROW + idx] = run;
                if (idx < NBINS) cur[idx] = run;
            }
            if (idx < NBINS) run += v[j];
        }
    }
    __syncthreads();

    // pass B: scatter slice into its private window, bin-sorted
    const int4*   src4 = (const int4*)src;
    const float4* w4   = (const float4*)w;
    uint2* out = binned + (size_t)bid * EPS;
#pragma unroll
    for (int j = 0; j < 7; ++j) {
        int idx = j * 256 + tid;
        if (idx < E4PS) {
            int4 d4 = dst4[i40 + idx];
            int4 s4 = src4[i40 + idx];
            float4 ww = w4[i40 + idx];
            int dd[4] = {d4.x, d4.y, d4.z, d4.w};
            int ss[4] = {s4.x, s4.y, s4.z, s4.w};
            float wv[4] = {ww.x, ww.y, ww.z, ww.w};
#pragma unroll
            for (int m = 0; m < 4; ++m) {
                int d = dd[m];
                int pos = atomicAdd(&cur[d >> 6], 1);  // LDS atomic, slice-local
                out[pos] = make_uint2(
                    (unsigned)ss[m] | ((unsigned)(d & 63) << 16),
                    __float_as_uint(wv[m]));
            }
        }
    }
}

// ---- kernel 2: per-bin gather across 250 slice ranges + sub-sort + epilogue ----
__global__ __launch_bounds__(256) void bin_gather3(
    const float* __restrict__ o_t, const float* __restrict__ E_t,
    const float* __restrict__ chem, const float* __restrict__ threshold,
    const float* __restrict__ decay, const int* __restrict__ hist,
    const uint2* __restrict__ binned,
    float* __restrict__ out_o, float* __restrict__ out_e) {
    __shared__ int   cnt_l[BSZ];
    __shared__ int   offs[BSZ + 1];
    __shared__ int   sc[BSZ];
    __shared__ uint2 eb[CAPE];      // ~20.5 KB

    const int k = blockIdx.x, tid = threadIdx.x;
    const int node0 = k * BSZ;
    const int nn = (NNODES - node0 < BSZ) ? (NNODES - node0) : BSZ;

    // my slice range for bin k
    int st = 0, c = 0;
    if (tid < K1B) {
        st = hist[(size_t)tid * HROW + k];
        int en = hist[(size_t)tid * HROW + k + 1];
        c = en - st;
    }
    const uint2* sb = binned + (size_t)tid * EPS + st;

    // A1: per-node histogram (pass 1 over my range)
    if (tid < BSZ) cnt_l[tid] = 0;
    __syncthreads();
    for (int j = 0; j < c; ++j)
        atomicAdd(&cnt_l[(sb[j].x >> 16) & 63], 1);
    __syncthreads();

    // A2: exclusive scan of 64 counts
    if (tid < BSZ) sc[tid] = cnt_l[tid];
    __syncthreads();
    for (int o = 1; o < BSZ; o <<= 1) {
        int v = (tid >= o && tid < BSZ) ? sc[tid - o] : 0;
        __syncthreads();
        if (tid < BSZ) sc[tid] += v;
        __syncthreads();
    }
    if (tid < BSZ) {
        int ex = sc[tid] - cnt_l[tid];
        offs[tid] = ex;
        cnt_l[tid] = ex;  // cursor
    }
    if (tid == 0) offs[BSZ] = sc[BSZ - 1];
    __syncthreads();

    // A3: pass 2 — copy into node-sorted LDS array
    for (int j = 0; j < c; ++j) {
        uint2 p = sb[j];
        int pos = atomicAdd(&cnt_l[(p.x >> 16) & 63], 1);
        if (pos < CAPE) eb[pos] = p;
    }
    __syncthreads();

    // B+C: one thread per (node, batch-quad); register accumulation; epilogue
    if (tid < nn * 4) {
        int n = tid >> 2;
        int q = (tid & 3) * 4;
        int gn = node0 + n;
        int e0 = offs[n], e1 = offs[n + 1];
        if (e1 > CAPE) e1 = CAPE;
        float4 en = *(const float4*)(E_t + (size_t)gn * BATCH + q);
        float4 acc = make_float4(0.f, 0.f, 0.f, 0.f);
        for (int i = e0; i < e1; ++i) {
            uint2 p = eb[i];  // quad's 4 lanes: same address -> broadcast
            float wv = __uint_as_float(p.y);
            int s = (int)(p.x & 0xFFFFu);
            float4 oj = *(const float4*)(o_t + (size_t)s * BATCH + q);
            acc.x += (oj.x >= en.x) ? oj.x * wv : -oj.x * wv;
            acc.y += (oj.y >= en.y) ? oj.y * wv : -oj.y * wv;
            acc.z += (oj.z >= en.z) ? oj.z * wv : -oj.z * wv;
            acc.w += (oj.w >= en.w) ? oj.w * wv : -oj.w * wv;
        }
        float th = threshold[gn];
        float dc = decay[gn];
        float ev[4] = {en.x, en.y, en.z, en.w};
        float av[4] = {acc.x, acc.y, acc.z, acc.w};
#pragma unroll
        for (int j = 0; j < 4; ++j) {
            int b = q + j;
            float e = ev[j];
            float S = e + chem[b * NNODES + gn] + av[j];
            S = fminf(fmaxf(S, CLAMP_LO), CLAMP_HI);
            float no = fmaxf(S - th, 0.0f);
            float ne;
            if (S > th) ne = no;
            else if (fabsf(S - e) <= EPS_V) ne = e - dc;
            else ne = S;
            out_o[b * NNODES + gn] = no;
            out_e[b * NNODES + gn] = ne;
        }
    }
}

// ---------- fallback: device-scope atomic path (needs no workspace) ----------
__global__ void edge_scatter_dev(const float* __restrict__ o_pre, const float* __restrict__ E,
                                 const float* __restrict__ w, const int* __restrict__ src,
                                 const int* __restrict__ dst, float* __restrict__ gj) {
    int e = blockIdx.x * blockDim.x + threadIdx.x;
    if (e >= NEDGES) return;
    int s = src[e];
    int d = dst[e];
    float wv = w[e];
#pragma unroll
    for (int b = 0; b < BATCH; ++b) {
        float oj = o_pre[b * NNODES + s];
        float en = E[b * NNODES + d];
        atomicAdd(&gj[b * NNODES + d], (oj >= en) ? oj * wv : -oj * wv);
    }
}

__global__ void finalize_dev(const float* __restrict__ chem, const float* __restrict__ E,
                             const float* __restrict__ threshold, const float* __restrict__ decay,
                             float* __restrict__ out_o, float* __restrict__ out_e_gj) {
    int i = blockIdx.x * blockDim.x + threadIdx.x;
    if (i >= BN) return;
    int n = i % NNODES;
    float e = E[i];
    float S = e + chem[i] + out_e_gj[i];
    S = fminf(fmaxf(S, CLAMP_LO), CLAMP_HI);
    float th = threshold[n];
    float no = fmaxf(S - th, 0.0f);
    float ne;
    if (S > th) ne = no;
    else if (fabsf(S - e) <= EPS_V) ne = e - decay[n];
    else ne = S;
    out_o[i] = no;
    out_e_gj[i] = ne;
}

extern "C" void kernel_launch(void* const* d_in, const int* in_sizes, int n_in,
                              void* d_out, int out_size, void* d_ws, size_t ws_size,
                              hipStream_t stream) {
    const float* chem      = (const float*)d_in[0];
    const float* E         = (const float*)d_in[1];
    const float* o_pre     = (const float*)d_in[2];
    const float* w         = (const float*)d_in[3];
    const float* threshold = (const float*)d_in[4];
    const float* decay     = (const float*)d_in[5];
    const int*   src       = (const int*)d_in[6];
    const int*   dst       = (const int*)d_in[7];

    float* out_o = (float*)d_out;
    float* out_e = (float*)d_out + BN;

    // ws layout (bytes, 16B-aligned):
    //   o_t:    [0,          3,200,000)
    //   E_t:    [3,200,000,  6,400,000)
    //   binned: [6,400,000, 19,200,000)   K1B*EPS uint2 = 12.8 MB
    //   hist:   [19,200,000, 19,984,000)  K1B*HROW ints = 784,000
    const size_t OT_OFF  = 0;
    const size_t ET_OFF  = 3200000;
    const size_t BIN_OFF = 6400000;
    const size_t H_OFF   = 19200000;
    const size_t need    = H_OFF + (size_t)K1B * HROW * sizeof(int);

    if (ws_size >= need) {
        char* ws = (char*)d_ws;
        float* o_t    = (float*)(ws + OT_OFF);
        float* E_t    = (float*)(ws + ET_OFF);
        uint2* binned = (uint2*)(ws + BIN_OFF);
        int*   hist   = (int*)(ws + H_OFF);

        slice_sort<<<K1B, 256, 0, stream>>>(o_pre, E, src, dst, w,
                                            o_t, E_t, hist, binned);
        bin_gather3<<<NBINS, 256, 0, stream>>>(o_t, E_t, chem, threshold, decay,
                                               hist, binned, out_o, out_e);
    } else {
        hipMemsetAsync(out_e, 0, (size_t)BN * sizeof(float), stream);
        edge_scatter_dev<<<(NEDGES + 255) / 256, 256, 0, stream>>>(o_pre, E, w, src, dst, out_e);
        finalize_dev<<<(BN + 255) / 256, 256, 0, stream>>>(chem, E, threshold, decay, out_o, out_e);
    }
}

// Round 15
// 142.788 us; speedup vs baseline: 1.0154x; 1.0154x over previous
//
#include <hip/hip_runtime.h>

#define BATCH 16
#define NNODES 50000
#define NEDGES 1600000
#define BN (BATCH * NNODES)
#define CLAMP_LO -10.0f
#define CLAMP_HI 10.0f
#define EPS_V 1e-6f

// ---- geometry ----
#define NBINS 782               // bins of 64 nodes; 782*64 = 50048 >= 50000
#define BSZ 64                  // nodes per bin
#define CAPE 2560               // LDS edge cap per bin: Poisson(2046) + 11.4 sd
#define K1B 250                 // kernel-1 blocks (slices)
#define EPS 6400                // edges per slice; 250*6400 = 1.6M exact
#define E4PS 1600               // int4s per slice
#define NPT 200                 // nodes transposed per k1 block; 250*200 = 50000
#define HROW 784                // hist row stride (783 starts, padded)

// ---- kernel 1: transpose + slice-local bin sort (deterministic, no global atomics) ----
__global__ __launch_bounds__(512) void slice_sort(
    const float* __restrict__ o_pre, const float* __restrict__ E,
    const int* __restrict__ src, const int* __restrict__ dst,
    const float* __restrict__ w,
    float* __restrict__ o_t, float* __restrict__ E_t,
    int* __restrict__ hist,        // [K1B][HROW] local bin starts (start[782]=6400)
    uint2* __restrict__ binned) {  // [K1B][EPS] slice-local, bin-sorted
    __shared__ int lh[NBINS];      // counts
    __shared__ int cur[NBINS];     // scatter cursors (slice-local)
    __shared__ int sm[512];
    const int tid = threadIdx.x, bid = blockIdx.x;

    for (int i = tid; i < NBINS; i += 512) lh[i] = 0;

    // transpose nodes [bid*200, bid*200+200)
    if (tid < NPT) {
        int t = bid * NPT + tid;
        float v[BATCH], u[BATCH];
#pragma unroll
        for (int b = 0; b < BATCH; ++b) {
            v[b] = o_pre[b * NNODES + t];   // coalesced across t
            u[b] = E[b * NNODES + t];
        }
        float4* op = (float4*)(o_t + (size_t)t * BATCH);
        float4* ep = (float4*)(E_t + (size_t)t * BATCH);
#pragma unroll
        for (int k = 0; k < 4; ++k) {
            op[k] = make_float4(v[4 * k], v[4 * k + 1], v[4 * k + 2], v[4 * k + 3]);
            ep[k] = make_float4(u[4 * k], u[4 * k + 1], u[4 * k + 2], u[4 * k + 3]);
        }
    }
    __syncthreads();  // lh zeroed

    // pass A: histogram this slice (int4 loads)
    const int4* dst4 = (const int4*)dst;
    const int i40 = bid * E4PS;
#pragma unroll
    for (int j = 0; j < 4; ++j) {
        int idx = j * 512 + tid;
        if (idx < E4PS) {
            int4 d4 = dst4[i40 + idx];
            atomicAdd(&lh[d4.x >> 6], 1);
            atomicAdd(&lh[d4.y >> 6], 1);
            atomicAdd(&lh[d4.z >> 6], 1);
            atomicAdd(&lh[d4.w >> 6], 1);
        }
    }
    __syncthreads();

    // block-scan 782 counts -> exclusive starts; thread t owns bins 2t, 2t+1
    {
        int base = tid * 2;
        int v[2], psum = 0;
#pragma unroll
        for (int j = 0; j < 2; ++j) {
            int idx = base + j;
            v[j] = (idx < NBINS) ? lh[idx] : 0;
            psum += v[j];
        }
        sm[tid] = psum;
        __syncthreads();
        for (int off = 1; off < 512; off <<= 1) {
            int a = (tid >= off) ? sm[tid - off] : 0;
            __syncthreads();
            sm[tid] += a;
            __syncthreads();
        }
        int run = (tid > 0) ? sm[tid - 1] : 0;
#pragma unroll
        for (int j = 0; j < 2; ++j) {
            int idx = base + j;
            if (idx < NBINS + 1) {           // write starts 0..782 (782 = total)
                hist[(size_t)bid * HROW + idx] = run;
                if (idx < NBINS) cur[idx] = run;
            }
            if (idx < NBINS) run += v[j];
        }
    }
    __syncthreads();

    // pass B: scatter slice into its private window, bin-sorted
    const int4*   src4 = (const int4*)src;
    const float4* w4   = (const float4*)w;
    uint2* out = binned + (size_t)bid * EPS;
#pragma unroll
    for (int j = 0; j < 4; ++j) {
        int idx = j * 512 + tid;
        if (idx < E4PS) {
            int4 d4 = dst4[i40 + idx];
            int4 s4 = src4[i40 + idx];
            float4 ww = w4[i40 + idx];
            int dd[4] = {d4.x, d4.y, d4.z, d4.w};
            int ss[4] = {s4.x, s4.y, s4.z, s4.w};
            float wv[4] = {ww.x, ww.y, ww.z, ww.w};
#pragma unroll
            for (int m = 0; m < 4; ++m) {
                int d = dd[m];
                int pos = atomicAdd(&cur[d >> 6], 1);  // LDS atomic, slice-local
                out[pos] = make_uint2(
                    (unsigned)ss[m] | ((unsigned)(d & 63) << 16),
                    __float_as_uint(wv[m]));
            }
        }
    }
}

// ---- kernel 2: per-bin gather, single global pass, LDS re-sort, fp2 phase B ----
__global__ __launch_bounds__(512) void bin_gather4(
    const float* __restrict__ o_t, const float* __restrict__ E_t,
    const float* __restrict__ chem, const float* __restrict__ threshold,
    const float* __restrict__ decay, const int* __restrict__ hist,
    const uint2* __restrict__ binned,
    float* __restrict__ out_o, float* __restrict__ out_e) {
    __shared__ int   cnt_l[BSZ];
    __shared__ int   offs[BSZ + 1];
    __shared__ int   sc[BSZ];
    __shared__ int   tot;
    __shared__ uint2 eb_raw[CAPE];  // 20.5 KB
    __shared__ uint2 ebs[CAPE];     // 20.5 KB

    const int k = blockIdx.x, tid = threadIdx.x;
    const int node0 = k * BSZ;
    const int nn = (NNODES - node0 < BSZ) ? (NNODES - node0) : BSZ;

    if (tid == 0) tot = 0;
    if (tid < BSZ) cnt_l[tid] = 0;
    __syncthreads();

    // A1: one global pass — copy my slice range into eb_raw + per-node counts
    if (tid < K1B) {
        int st = hist[(size_t)tid * HROW + k];
        int en = hist[(size_t)tid * HROW + k + 1];
        int c = en - st;
        if (c > 0) {
            int p0 = atomicAdd(&tot, c);
            const uint2* sb = binned + (size_t)tid * EPS + st;
            for (int j = 0; j < c; ++j) {
                uint2 p = sb[j];
                if (p0 + j < CAPE) eb_raw[p0 + j] = p;
                atomicAdd(&cnt_l[(p.x >> 16) & 63], 1);
            }
        }
    }
    __syncthreads();
    int total = tot;
    if (total > CAPE) total = CAPE;

    // A2: exclusive scan of 64 counts
    if (tid < BSZ) sc[tid] = cnt_l[tid];
    __syncthreads();
    for (int o = 1; o < BSZ; o <<= 1) {
        int v = (tid >= o && tid < BSZ) ? sc[tid - o] : 0;
        __syncthreads();
        if (tid < BSZ) sc[tid] += v;
        __syncthreads();
    }
    if (tid < BSZ) {
        int ex = sc[tid] - cnt_l[tid];
        offs[tid] = ex;
        cnt_l[tid] = ex;  // cursor
    }
    if (tid == 0) offs[BSZ] = sc[BSZ - 1];
    __syncthreads();

    // A3: LDS -> LDS node sort
    for (int i = tid; i < total; i += 512) {
        uint2 p = eb_raw[i];
        int pos = atomicAdd(&cnt_l[(p.x >> 16) & 63], 1);
        if (pos < CAPE) ebs[pos] = p;
    }
    __syncthreads();

    // B+C: one thread per (node, batch-pair); float2 register accumulation; epilogue
    if (tid < nn * 8) {
        int n = tid >> 3;
        int b0 = (tid & 7) * 2;
        int gn = node0 + n;
        int e0 = offs[n], e1 = offs[n + 1];
        if (e1 > CAPE) e1 = CAPE;
        float2 en2 = *(const float2*)(E_t + (size_t)gn * BATCH + b0);
        float ax = 0.f, ay = 0.f;
#pragma unroll 4
        for (int i = e0; i < e1; ++i) {
            uint2 p = ebs[i];  // 8 lanes of the node: same address -> broadcast
            float wv = __uint_as_float(p.y);
            int s = (int)(p.x & 0xFFFFu);
            float2 oj = *(const float2*)(o_t + (size_t)s * BATCH + b0);
            ax += (oj.x >= en2.x) ? oj.x * wv : -oj.x * wv;
            ay += (oj.y >= en2.y) ? oj.y * wv : -oj.y * wv;
        }
        float th = threshold[gn];
        float dc = decay[gn];
        float ev[2] = {en2.x, en2.y};
        float av[2] = {ax, ay};
#pragma unroll
        for (int j = 0; j < 2; ++j) {
            int b = b0 + j;
            float e = ev[j];
            float S = e + chem[b * NNODES + gn] + av[j];
            S = fminf(fmaxf(S, CLAMP_LO), CLAMP_HI);
            float no = fmaxf(S - th, 0.0f);
            float ne;
            if (S > th) ne = no;
            else if (fabsf(S - e) <= EPS_V) ne = e - dc;
            else ne = S;
            out_o[b * NNODES + gn] = no;
            out_e[b * NNODES + gn] = ne;
        }
    }
}

// ---------- fallback: device-scope atomic path (needs no workspace) ----------
__global__ void edge_scatter_dev(const float* __restrict__ o_pre, const float* __restrict__ E,
                                 const float* __restrict__ w, const int* __restrict__ src,
                                 const int* __restrict__ dst, float* __restrict__ gj) {
    int e = blockIdx.x * blockDim.x + threadIdx.x;
    if (e >= NEDGES) return;
    int s = src[e];
    int d = dst[e];
    float wv = w[e];
#pragma unroll
    for (int b = 0; b < BATCH; ++b) {
        float oj = o_pre[b * NNODES + s];
        float en = E[b * NNODES + d];
        atomicAdd(&gj[b * NNODES + d], (oj >= en) ? oj * wv : -oj * wv);
    }
}

__global__ void finalize_dev(const float* __restrict__ chem, const float* __restrict__ E,
                             const float* __restrict__ threshold, const float* __restrict__ decay,
                             float* __restrict__ out_o, float* __restrict__ out_e_gj) {
    int i = blockIdx.x * blockDim.x + threadIdx.x;
    if (i >= BN) return;
    int n = i % NNODES;
    float e = E[i];
    float S = e + chem[i] + out_e_gj[i];
    S = fminf(fmaxf(S, CLAMP_LO), CLAMP_HI);
    float th = threshold[n];
    float no = fmaxf(S - th, 0.0f);
    float ne;
    if (S > th) ne = no;
    else if (fabsf(S - e) <= EPS_V) ne = e - decay[n];
    else ne = S;
    out_o[i] = no;
    out_e_gj[i] = ne;
}

extern "C" void kernel_launch(void* const* d_in, const int* in_sizes, int n_in,
                              void* d_out, int out_size, void* d_ws, size_t ws_size,
                              hipStream_t stream) {
    const float* chem      = (const float*)d_in[0];
    const float* E         = (const float*)d_in[1];
    const float* o_pre     = (const float*)d_in[2];
    const float* w         = (const float*)d_in[3];
    const float* threshold = (const float*)d_in[4];
    const float* decay     = (const float*)d_in[5];
    const int*   src       = (const int*)d_in[6];
    const int*   dst       = (const int*)d_in[7];

    float* out_o = (float*)d_out;
    float* out_e = (float*)d_out + BN;

    // ws layout (bytes, 16B-aligned):
    //   o_t:    [0,          3,200,000)
    //   E_t:    [3,200,000,  6,400,000)
    //   binned: [6,400,000, 19,200,000)   K1B*EPS uint2 = 12.8 MB
    //   hist:   [19,200,000, 19,984,000)  K1B*HROW ints = 784,000
    const size_t OT_OFF  = 0;
    const size_t ET_OFF  = 3200000;
    const size_t BIN_OFF = 6400000;
    const size_t H_OFF   = 19200000;
    const size_t need    = H_OFF + (size_t)K1B * HROW * sizeof(int);

    if (ws_size >= need) {
        char* ws = (char*)d_ws;
        float* o_t    = (float*)(ws + OT_OFF);
        float* E_t    = (float*)(ws + ET_OFF);
        uint2* binned = (uint2*)(ws + BIN_OFF);
        int*   hist   = (int*)(ws + H_OFF);

        slice_sort<<<K1B, 512, 0, stream>>>(o_pre, E, src, dst, w,
                                            o_t, E_t, hist, binned);
        bin_gather4<<<NBINS, 512, 0, stream>>>(o_t, E_t, chem, threshold, decay,
                                               hist, binned, out_o, out_e);
    } else {
        hipMemsetAsync(out_e, 0, (size_t)BN * sizeof(float), stream);
        edge_scatter_dev<<<(NEDGES + 255) / 256, 256, 0, stream>>>(o_pre, E, w, src, dst, out_e);
        finalize_dev<<<(BN + 255) / 256, 256, 0, stream>>>(chem, E, threshold, decay, out_o, out_e);
    }
}

// Round 16
// 130.853 us; speedup vs baseline: 1.1080x; 1.0912x over previous
//
#include <hip/hip_runtime.h>

#define BATCH 16
#define NNODES 50000
#define NEDGES 1600000
#define BN (BATCH * NNODES)
#define NBLK 391                 // binning blocks; 391*4096 >= NEDGES
#define EPB 4096                 // edges per binning block
#define BSZ 128                  // nodes per bin
#define NBINS 391                // ceil(NNODES/BSZ); last bin has 80 nodes
#define CAPE 4992                // fixed per-bin capacity (mean 4092, +14 sd)
#define CLAMP_LO -10.0f
#define CLAMP_HI 10.0f
#define EPS_V 1e-6f

// ---- pass 1: fused transpose (o_pre,E -> (N,16)) + coarse histogram ----
__global__ __launch_bounds__(256) void prep_hist_kernel(
    const float* __restrict__ o_pre, const float* __restrict__ E,
    const int* __restrict__ dst,
    float* __restrict__ o_t, float* __restrict__ E_t,
    int* __restrict__ hist) {
    __shared__ int lh[NBINS];
    const int tid = threadIdx.x, bid = blockIdx.x;
    for (int i = tid; i < NBINS; i += 256) lh[i] = 0;

    // transpose slice: 128 nodes per block (391*128 = 50048 >= 50000)
    if (tid < 128) {
        int t = bid * 128 + tid;
        if (t < NNODES) {
            float v[BATCH], u[BATCH];
#pragma unroll
            for (int b = 0; b < BATCH; ++b) {
                v[b] = o_pre[b * NNODES + t];  // coalesced across t
                u[b] = E[b * NNODES + t];
            }
            float4* op = (float4*)(o_t + (size_t)t * BATCH);
            float4* ep = (float4*)(E_t + (size_t)t * BATCH);
#pragma unroll
            for (int k = 0; k < 4; ++k) {
                op[k] = make_float4(v[4 * k], v[4 * k + 1], v[4 * k + 2], v[4 * k + 3]);
                ep[k] = make_float4(u[4 * k], u[4 * k + 1], u[4 * k + 2], u[4 * k + 3]);
            }
        }
    }
    __syncthreads();  // lh zeroed

    // histogram slice: int4 edge reads (4 edges / instruction)
    const int4* dst4 = (const int4*)dst;
    const int e4base = bid * (EPB / 4);
#pragma unroll
    for (int j = 0; j < 4; ++j) {
        int i4 = e4base + j * 256 + tid;
        if (i4 * 4 < NEDGES) {  // NEDGES % 4 == 0
            int4 d4 = dst4[i4];
            atomicAdd(&lh[d4.x >> 7], 1);
            atomicAdd(&lh[d4.y >> 7], 1);
            atomicAdd(&lh[d4.z >> 7], 1);
            atomicAdd(&lh[d4.w >> 7], 1);
        }
    }
    __syncthreads();
    for (int i = tid; i < NBINS; i += 256) hist[i * NBLK + bid] = lh[i];
}

// ---- pass 2: per-bin exclusive scan over the 391 block counts ----
__global__ __launch_bounds__(256) void scanA_kernel(int* __restrict__ hist,
                                                    int* __restrict__ totals) {
    __shared__ int sm[256];
    const int k = blockIdx.x, t = threadIdx.x;
    const int base = t * 2;
    int v0 = (base < NBLK) ? hist[k * NBLK + base] : 0;
    int v1 = (base + 1 < NBLK) ? hist[k * NBLK + base + 1] : 0;
    sm[t] = v0 + v1;
    __syncthreads();
    for (int off = 1; off < 256; off <<= 1) {
        int a = (t >= off) ? sm[t - off] : 0;
        __syncthreads();
        sm[t] += a;
        __syncthreads();
    }
    int run = (t > 0) ? sm[t - 1] : 0;
    if (base < NBLK) { hist[k * NBLK + base] = run; run += v0; }
    if (base + 1 < NBLK) hist[k * NBLK + base + 1] = run;
    if (t == 255) totals[k] = sm[255];
}

// ---- pass 3: scatter edges into fixed-stride bins, deterministic slots ----
__global__ __launch_bounds__(256) void scatterA_kernel(
    const int* __restrict__ src, const int* __restrict__ dst,
    const float* __restrict__ w, const int* __restrict__ hist,
    uint2* __restrict__ binned) {
    __shared__ int cur[NBINS];
    const int tid = threadIdx.x, bid = blockIdx.x;
    for (int i = tid; i < NBINS; i += 256)
        cur[i] = i * CAPE + hist[i * NBLK + bid];
    __syncthreads();
    const int4*   dst4 = (const int4*)dst;
    const int4*   src4 = (const int4*)src;
    const float4* w4   = (const float4*)w;
    const int e4base = bid * (EPB / 4);
#pragma unroll
    for (int j = 0; j < 4; ++j) {
        int i4 = e4base + j * 256 + tid;
        if (i4 * 4 < NEDGES) {
            int4 d4 = dst4[i4];
            int4 s4 = src4[i4];
            float4 ww = w4[i4];
            int dd[4] = {d4.x, d4.y, d4.z, d4.w};
            int ss[4] = {s4.x, s4.y, s4.z, s4.w};
            float wv[4] = {ww.x, ww.y, ww.z, ww.w};
#pragma unroll
            for (int m = 0; m < 4; ++m) {
                int d = dd[m];
                int bin = d >> 7;
                int pos = atomicAdd(&cur[bin], 1);  // LDS atomic
                if (pos < (bin + 1) * CAPE)         // overflow guard (never fires)
                    binned[pos] = make_uint2(
                        (unsigned)ss[m] | ((unsigned)(d & 127) << 16),
                        __float_as_uint(wv[m]));
            }
        }
    }
}

// ---- pass 4: per-bin node sub-sort in LDS, register accumulation, epilogue ----
// (byte-identical logic to round 11's validated bin_gather2)
__global__ __launch_bounds__(512) void bin_gather2(
    const float* __restrict__ o_t, const float* __restrict__ E_t,
    const float* __restrict__ chem, const float* __restrict__ threshold,
    const float* __restrict__ decay, const int* __restrict__ totals,
    const uint2* __restrict__ binned,
    float* __restrict__ out_o, float* __restrict__ out_e) {
    __shared__ int   cnt_l[BSZ];
    __shared__ int   offs[BSZ + 1];
    __shared__ int   sc[BSZ];
    __shared__ uint2 eb[CAPE];  // ~40 KB
    const int k = blockIdx.x, tid = threadIdx.x;
    const int node0 = k * BSZ;
    const int nn = (NNODES - node0 < BSZ) ? (NNODES - node0) : BSZ;
    const int s0 = k * CAPE;
    int cnt = totals[k];
    if (cnt > CAPE) cnt = CAPE;
    const int s1 = s0 + cnt;

    if (tid < BSZ) cnt_l[tid] = 0;
    __syncthreads();
    for (int i = s0 + tid; i < s1; i += 512)
        atomicAdd(&cnt_l[(binned[i].x >> 16) & 127], 1);
    __syncthreads();
    if (tid < BSZ) sc[tid] = cnt_l[tid];
    __syncthreads();
    for (int o = 1; o < BSZ; o <<= 1) {
        int v = (tid >= o && tid < BSZ) ? sc[tid - o] : 0;
        __syncthreads();
        if (tid < BSZ) sc[tid] += v;
        __syncthreads();
    }
    if (tid < BSZ) {
        int ex = sc[tid] - cnt_l[tid];
        offs[tid] = ex;
        cnt_l[tid] = ex;
    }
    if (tid == 0) offs[BSZ] = cnt;
    __syncthreads();
    for (int i = s0 + tid; i < s1; i += 512) {
        uint2 p = binned[i];
        int pos = atomicAdd(&cnt_l[(p.x >> 16) & 127], 1);
        if (pos < CAPE) eb[pos] = p;
    }
    __syncthreads();

    for (int t = tid; t < nn * 4; t += 512) {
        int n = t >> 2;
        int q = (t & 3) * 4;
        int gn = node0 + n;
        int e0 = offs[n], e1 = offs[n + 1];
        float4 en = *(const float4*)(E_t + (size_t)gn * BATCH + q);
        float4 acc = make_float4(0.f, 0.f, 0.f, 0.f);
        for (int i = e0; i < e1; ++i) {
            uint2 p = eb[i];  // quad's 4 lanes: same address -> broadcast
            float wv = __uint_as_float(p.y);
            int s = (int)(p.x & 0xFFFFu);
            float4 oj = *(const float4*)(o_t + (size_t)s * BATCH + q);
            acc.x += (oj.x >= en.x) ? oj.x * wv : -oj.x * wv;
            acc.y += (oj.y >= en.y) ? oj.y * wv : -oj.y * wv;
            acc.z += (oj.z >= en.z) ? oj.z * wv : -oj.z * wv;
            acc.w += (oj.w >= en.w) ? oj.w * wv : -oj.w * wv;
        }
        float th = threshold[gn];
        float dc = decay[gn];
        float ev[4] = {en.x, en.y, en.z, en.w};
        float av[4] = {acc.x, acc.y, acc.z, acc.w};
#pragma unroll
        for (int j = 0; j < 4; ++j) {
            int b = q + j;
            float e = ev[j];
            float S = e + chem[b * NNODES + gn] + av[j];
            S = fminf(fmaxf(S, CLAMP_LO), CLAMP_HI);
            float no = fmaxf(S - th, 0.0f);
            float ne;
            if (S > th) ne = no;
            else if (fabsf(S - e) <= EPS_V) ne = e - dc;
            else ne = S;
            out_o[b * NNODES + gn] = no;
            out_e[b * NNODES + gn] = ne;
        }
    }
}

// ---------- fallback: device-scope atomic path (needs no workspace) ----------
__global__ void edge_scatter_dev(const float* __restrict__ o_pre, const float* __restrict__ E,
                                 const float* __restrict__ w, const int* __restrict__ src,
                                 const int* __restrict__ dst, float* __restrict__ gj) {
    int e = blockIdx.x * blockDim.x + threadIdx.x;
    if (e >= NEDGES) return;
    int s = src[e];
    int d = dst[e];
    float wv = w[e];
#pragma unroll
    for (int b = 0; b < BATCH; ++b) {
        float oj = o_pre[b * NNODES + s];
        float en = E[b * NNODES + d];
        atomicAdd(&gj[b * NNODES + d], (oj >= en) ? oj * wv : -oj * wv);
    }
}

__global__ void finalize_dev(const float* __restrict__ chem, const float* __restrict__ E,
                             const float* __restrict__ threshold, const float* __restrict__ decay,
                             float* __restrict__ out_o, float* __restrict__ out_e_gj) {
    int i = blockIdx.x * blockDim.x + threadIdx.x;
    if (i >= BN) return;
    int n = i % NNODES;
    float e = E[i];
    float S = e + chem[i] + out_e_gj[i];
    S = fminf(fmaxf(S, CLAMP_LO), CLAMP_HI);
    float th = threshold[n];
    float no = fmaxf(S - th, 0.0f);
    float ne;
    if (S > th) ne = no;
    else if (fabsf(S - e) <= EPS_V) ne = e - decay[n];
    else ne = S;
    out_o[i] = no;
    out_e_gj[i] = ne;
}

extern "C" void kernel_launch(void* const* d_in, const int* in_sizes, int n_in,
                              void* d_out, int out_size, void* d_ws, size_t ws_size,
                              hipStream_t stream) {
    const float* chem      = (const float*)d_in[0];
    const float* E         = (const float*)d_in[1];
    const float* o_pre     = (const float*)d_in[2];
    const float* w         = (const float*)d_in[3];
    const float* threshold = (const float*)d_in[4];
    const float* decay     = (const float*)d_in[5];
    const int*   src       = (const int*)d_in[6];
    const int*   dst       = (const int*)d_in[7];

    float* out_o = (float*)d_out;
    float* out_e = (float*)d_out + BN;

    // ws layout (bytes, 16B-aligned):
    //   o_t:    [0,          3,200,000)
    //   E_t:    [3,200,000,  6,400,000)
    //   binned: [6,400,000, 22,014,976)   NBINS*CAPE uint2 = 15,614,976
    //   hist:   [22,014,976, 22,626,500)  NBINS*NBLK ints = 611,524
    //   totals: [22,626,512, 22,628,076)  NBINS ints
    const size_t OT_OFF  = 0;
    const size_t ET_OFF  = 3200000;
    const size_t BIN_OFF = 6400000;
    const size_t H_OFF   = 22014976;
    const size_t TOT_OFF = 22626512;
    const size_t need    = TOT_OFF + (size_t)NBINS * sizeof(int);

    if (ws_size >= need) {
        char* ws = (char*)d_ws;
        float* o_t    = (float*)(ws + OT_OFF);
        float* E_t    = (float*)(ws + ET_OFF);
        uint2* binned = (uint2*)(ws + BIN_OFF);
        int*   hist   = (int*)(ws + H_OFF);
        int*   totals = (int*)(ws + TOT_OFF);

        prep_hist_kernel<<<NBLK, 256, 0, stream>>>(o_pre, E, dst, o_t, E_t, hist);
        scanA_kernel<<<NBINS, 256, 0, stream>>>(hist, totals);
        scatterA_kernel<<<NBLK, 256, 0, stream>>>(src, dst, w, hist, binned);
        bin_gather2<<<NBINS, 512, 0, stream>>>(o_t, E_t, chem, threshold, decay,
                                               totals, binned, out_o, out_e);
    } else {
        hipMemsetAsync(out_e, 0, (size_t)BN * sizeof(float), stream);
        edge_scatter_dev<<<(NEDGES + 255) / 256, 256, 0, stream>>>(o_pre, E, w, src, dst, out_e);
        finalize_dev<<<(BN + 255) / 256, 256, 0, stream>>>(chem, E, threshold, decay, out_o, out_e);
    }
}

// Round 17
// 130.521 us; speedup vs baseline: 1.1109x; 1.0025x over previous
//
#include <hip/hip_runtime.h>

#define BATCH 16
#define NNODES 50000
#define NEDGES 1600000
#define BN (BATCH * NNODES)
#define NBLK 391                 // binning blocks; 391*4096 >= NEDGES
#define EPB 4096                 // edges per binning block
#define BSZ 128                  // nodes per bin
#define NBINS 391                // ceil(NNODES/BSZ); last bin has 80 nodes
#define CAPE 4992                // fixed per-bin capacity (mean 4092, +14 sd)
#define RPT 10                   // register-cached entries/thread: 10*512 >= CAPE
#define CLAMP_LO -10.0f
#define CLAMP_HI 10.0f
#define EPS_V 1e-6f

// ---- pass 1: fused transpose (o_pre,E -> (N,16)) + coarse histogram ----
__global__ __launch_bounds__(256) void prep_hist_kernel(
    const float* __restrict__ o_pre, const float* __restrict__ E,
    const int* __restrict__ dst,
    float* __restrict__ o_t, float* __restrict__ E_t,
    int* __restrict__ hist) {
    __shared__ int lh[NBINS];
    const int tid = threadIdx.x, bid = blockIdx.x;
    for (int i = tid; i < NBINS; i += 256) lh[i] = 0;

    if (tid < 128) {
        int t = bid * 128 + tid;
        if (t < NNODES) {
            float v[BATCH], u[BATCH];
#pragma unroll
            for (int b = 0; b < BATCH; ++b) {
                v[b] = o_pre[b * NNODES + t];  // coalesced across t
                u[b] = E[b * NNODES + t];
            }
            float4* op = (float4*)(o_t + (size_t)t * BATCH);
            float4* ep = (float4*)(E_t + (size_t)t * BATCH);
#pragma unroll
            for (int k = 0; k < 4; ++k) {
                op[k] = make_float4(v[4 * k], v[4 * k + 1], v[4 * k + 2], v[4 * k + 3]);
                ep[k] = make_float4(u[4 * k], u[4 * k + 1], u[4 * k + 2], u[4 * k + 3]);
            }
        }
    }
    __syncthreads();  // lh zeroed

    const int4* dst4 = (const int4*)dst;
    const int e4base = bid * (EPB / 4);
#pragma unroll
    for (int j = 0; j < 4; ++j) {
        int i4 = e4base + j * 256 + tid;
        if (i4 * 4 < NEDGES) {
            int4 d4 = dst4[i4];
            atomicAdd(&lh[d4.x >> 7], 1);
            atomicAdd(&lh[d4.y >> 7], 1);
            atomicAdd(&lh[d4.z >> 7], 1);
            atomicAdd(&lh[d4.w >> 7], 1);
        }
    }
    __syncthreads();
    for (int i = tid; i < NBINS; i += 256) hist[i * NBLK + bid] = lh[i];
}

// ---- pass 2: per-bin exclusive scan over the 391 block counts ----
__global__ __launch_bounds__(256) void scanA_kernel(int* __restrict__ hist,
                                                    int* __restrict__ totals) {
    __shared__ int sm[256];
    const int k = blockIdx.x, t = threadIdx.x;
    const int base = t * 2;
    int v0 = (base < NBLK) ? hist[k * NBLK + base] : 0;
    int v1 = (base + 1 < NBLK) ? hist[k * NBLK + base + 1] : 0;
    sm[t] = v0 + v1;
    __syncthreads();
    for (int off = 1; off < 256; off <<= 1) {
        int a = (t >= off) ? sm[t - off] : 0;
        __syncthreads();
        sm[t] += a;
        __syncthreads();
    }
    int run = (t > 0) ? sm[t - 1] : 0;
    if (base < NBLK) { hist[k * NBLK + base] = run; run += v0; }
    if (base + 1 < NBLK) hist[k * NBLK + base + 1] = run;
    if (t == 255) totals[k] = sm[255];
}

// ---- pass 3: scatter edges into fixed-stride bins, deterministic slots ----
__global__ __launch_bounds__(256) void scatterA_kernel(
    const int* __restrict__ src, const int* __restrict__ dst,
    const float* __restrict__ w, const int* __restrict__ hist,
    uint2* __restrict__ binned) {
    __shared__ int cur[NBINS];
    const int tid = threadIdx.x, bid = blockIdx.x;
    for (int i = tid; i < NBINS; i += 256)
        cur[i] = i * CAPE + hist[i * NBLK + bid];
    __syncthreads();
    const int4*   dst4 = (const int4*)dst;
    const int4*   src4 = (const int4*)src;
    const float4* w4   = (const float4*)w;
    const int e4base = bid * (EPB / 4);
#pragma unroll
    for (int j = 0; j < 4; ++j) {
        int i4 = e4base + j * 256 + tid;
        if (i4 * 4 < NEDGES) {
            int4 d4 = dst4[i4];
            int4 s4 = src4[i4];
            float4 ww = w4[i4];
            int dd[4] = {d4.x, d4.y, d4.z, d4.w};
            int ss[4] = {s4.x, s4.y, s4.z, s4.w};
            float wv[4] = {ww.x, ww.y, ww.z, ww.w};
#pragma unroll
            for (int m = 0; m < 4; ++m) {
                int d = dd[m];
                int bin = d >> 7;
                int pos = atomicAdd(&cur[bin], 1);  // LDS atomic
                if (pos < (bin + 1) * CAPE)
                    binned[pos] = make_uint2(
                        (unsigned)ss[m] | ((unsigned)(d & 127) << 16),
                        __float_as_uint(wv[m]));
            }
        }
    }
}

// ---- pass 4: register-cached single-read sub-sort + register accumulation ----
__global__ __launch_bounds__(512) void bin_gather5(
    const float* __restrict__ o_t, const float* __restrict__ E_t,
    const float* __restrict__ chem, const float* __restrict__ threshold,
    const float* __restrict__ decay, const int* __restrict__ totals,
    const uint2* __restrict__ binned,
    float* __restrict__ out_o, float* __restrict__ out_e) {
    __shared__ int   cnt_l[BSZ];
    __shared__ int   offs[BSZ + 1];
    __shared__ int   sc[BSZ];
    __shared__ uint2 eb[CAPE];  // ~40 KB
    const int k = blockIdx.x, tid = threadIdx.x;
    const int node0 = k * BSZ;
    const int nn = (NNODES - node0 < BSZ) ? (NNODES - node0) : BSZ;
    const int s0 = k * CAPE;
    int cnt = totals[k];
    if (cnt > CAPE) cnt = CAPE;

    // A1: ONE coalesced global pass -> register cache + per-node counts
    uint2 r[RPT];
    if (tid < BSZ) cnt_l[tid] = 0;
    __syncthreads();
#pragma unroll
    for (int j = 0; j < RPT; ++j) {
        int idx = tid + j * 512;
        if (idx < cnt) {
            uint2 p = binned[s0 + idx];
            r[j] = p;
            atomicAdd(&cnt_l[(p.x >> 16) & 127], 1);
        }
    }
    __syncthreads();

    // A2: exclusive scan of 128 counts
    if (tid < BSZ) sc[tid] = cnt_l[tid];
    __syncthreads();
    for (int o = 1; o < BSZ; o <<= 1) {
        int v = (tid >= o && tid < BSZ) ? sc[tid - o] : 0;
        __syncthreads();
        if (tid < BSZ) sc[tid] += v;
        __syncthreads();
    }
    if (tid < BSZ) {
        int ex = sc[tid] - cnt_l[tid];
        offs[tid] = ex;
        cnt_l[tid] = ex;  // cursor
    }
    if (tid == 0) offs[BSZ] = cnt;
    __syncthreads();

    // A3: scatter from registers into node-sorted LDS array
#pragma unroll
    for (int j = 0; j < RPT; ++j) {
        int idx = tid + j * 512;
        if (idx < cnt) {
            uint2 p = r[j];
            int pos = atomicAdd(&cnt_l[(p.x >> 16) & 127], 1);
            if (pos < CAPE) eb[pos] = p;
        }
    }
    __syncthreads();

    // B+C: one thread per (node, batch-quad); register accumulation; epilogue
    for (int t = tid; t < nn * 4; t += 512) {
        int n = t >> 2;
        int q = (t & 3) * 4;
        int gn = node0 + n;
        int e0 = offs[n], e1 = offs[n + 1];
        float4 en = *(const float4*)(E_t + (size_t)gn * BATCH + q);
        float4 acc = make_float4(0.f, 0.f, 0.f, 0.f);
        for (int i = e0; i < e1; ++i) {
            uint2 p = eb[i];  // quad's 4 lanes: same address -> broadcast
            float wv = __uint_as_float(p.y);
            int s = (int)(p.x & 0xFFFFu);
            float4 oj = *(const float4*)(o_t + (size_t)s * BATCH + q);
            acc.x += (oj.x >= en.x) ? oj.x * wv : -oj.x * wv;
            acc.y += (oj.y >= en.y) ? oj.y * wv : -oj.y * wv;
            acc.z += (oj.z >= en.z) ? oj.z * wv : -oj.z * wv;
            acc.w += (oj.w >= en.w) ? oj.w * wv : -oj.w * wv;
        }
        float th = threshold[gn];
        float dc = decay[gn];
        float ev[4] = {en.x, en.y, en.z, en.w};
        float av[4] = {acc.x, acc.y, acc.z, acc.w};
#pragma unroll
        for (int j = 0; j < 4; ++j) {
            int b = q + j;
            float e = ev[j];
            float S = e + chem[b * NNODES + gn] + av[j];
            S = fminf(fmaxf(S, CLAMP_LO), CLAMP_HI);
            float no = fmaxf(S - th, 0.0f);
            float ne;
            if (S > th) ne = no;
            else if (fabsf(S - e) <= EPS_V) ne = e - dc;
            else ne = S;
            out_o[b * NNODES + gn] = no;
            out_e[b * NNODES + gn] = ne;
        }
    }
}

// ---------- fallback: device-scope atomic path (needs no workspace) ----------
__global__ void edge_scatter_dev(const float* __restrict__ o_pre, const float* __restrict__ E,
                                 const float* __restrict__ w, const int* __restrict__ src,
                                 const int* __restrict__ dst, float* __restrict__ gj) {
    int e = blockIdx.x * blockDim.x + threadIdx.x;
    if (e >= NEDGES) return;
    int s = src[e];
    int d = dst[e];
    float wv = w[e];
#pragma unroll
    for (int b = 0; b < BATCH; ++b) {
        float oj = o_pre[b * NNODES + s];
        float en = E[b * NNODES + d];
        atomicAdd(&gj[b * NNODES + d], (oj >= en) ? oj * wv : -oj * wv);
    }
}

__global__ void finalize_dev(const float* __restrict__ chem, const float* __restrict__ E,
                             const float* __restrict__ threshold, const float* __restrict__ decay,
                             float* __restrict__ out_o, float* __restrict__ out_e_gj) {
    int i = blockIdx.x * blockDim.x + threadIdx.x;
    if (i >= BN) return;
    int n = i % NNODES;
    float e = E[i];
    float S = e + chem[i] + out_e_gj[i];
    S = fminf(fmaxf(S, CLAMP_LO), CLAMP_HI);
    float th = threshold[n];
    float no = fmaxf(S - th, 0.0f);
    float ne;
    if (S > th) ne = no;
    else if (fabsf(S - e) <= EPS_V) ne = e - decay[n];
    else ne = S;
    out_o[i] = no;
    out_e_gj[i] = ne;
}

extern "C" void kernel_launch(void* const* d_in, const int* in_sizes, int n_in,
                              void* d_out, int out_size, void* d_ws, size_t ws_size,
                              hipStream_t stream) {
    const float* chem      = (const float*)d_in[0];
    const float* E         = (const float*)d_in[1];
    const float* o_pre     = (const float*)d_in[2];
    const float* w         = (const float*)d_in[3];
    const float* threshold = (const float*)d_in[4];
    const float* decay     = (const float*)d_in[5];
    const int*   src       = (const int*)d_in[6];
    const int*   dst       = (const int*)d_in[7];

    float* out_o = (float*)d_out;
    float* out_e = (float*)d_out + BN;

    const size_t OT_OFF  = 0;
    const size_t ET_OFF  = 3200000;
    const size_t BIN_OFF = 6400000;
    const size_t H_OFF   = 22014976;
    const size_t TOT_OFF = 22626512;
    const size_t need    = TOT_OFF + (size_t)NBINS * sizeof(int);

    if (ws_size >= need) {
        char* ws = (char*)d_ws;
        float* o_t    = (float*)(ws + OT_OFF);
        float* E_t    = (float*)(ws + ET_OFF);
        uint2* binned = (uint2*)(ws + BIN_OFF);
        int*   hist   = (int*)(ws + H_OFF);
        int*   totals = (int*)(ws + TOT_OFF);

        prep_hist_kernel<<<NBLK, 256, 0, stream>>>(o_pre, E, dst, o_t, E_t, hist);
        scanA_kernel<<<NBINS, 256, 0, stream>>>(hist, totals);
        scatterA_kernel<<<NBLK, 256, 0, stream>>>(src, dst, w, hist, binned);
        bin_gather5<<<NBINS, 512, 0, stream>>>(o_t, E_t, chem, threshold, decay,
                                               totals, binned, out_o, out_e);
    } else {
        hipMemsetAsync(out_e, 0, (size_t)BN * sizeof(float), stream);
        edge_scatter_dev<<<(NEDGES + 255) / 256, 256, 0, stream>>>(o_pre, E, w, src, dst, out_e);
        finalize_dev<<<(BN + 255) / 256, 256, 0, stream>>>(chem, E, threshold, decay, out_o, out_e);
    }
}